// Round 2
// baseline (4703.056 us; speedup 1.0000x reference)
//
#include <hip/hip_runtime.h>

#define N_NODES 100000
#define BATCH   256
#define NUM_TAU 4
#define ORDER   8
#define NB      (N_NODES * BATCH)   // 25,600,000 elements per tau slice

// ---------------- CSR build ----------------

__global__ void hist_kernel(const int* __restrict__ dst, int* __restrict__ counts, int E) {
    int e = blockIdx.x * blockDim.x + threadIdx.x;
    if (e < E) atomicAdd(&counts[dst[e]], 1);
}

__global__ void alloc_kernel(const int* __restrict__ counts, int* __restrict__ rowStart,
                             int* __restrict__ cursor, int* __restrict__ totalCursor) {
    int n = blockIdx.x * blockDim.x + threadIdx.x;
    if (n < N_NODES) {
        int len = counts[n];
        int start = atomicAdd(totalCursor, len);
        rowStart[n] = start;
        cursor[n] = start;
    }
}

__global__ void scatter_kernel(const int* __restrict__ src, const int* __restrict__ dst,
                               const float* __restrict__ w, int* __restrict__ cursor,
                               int2* __restrict__ csr_pair, int E) {
    int e = blockIdx.x * blockDim.x + threadIdx.x;
    if (e < E) {
        int d = dst[e];
        int p = atomicAdd(&cursor[d], 1);
        int2 pr;
        pr.x = src[e];
        pr.y = __float_as_int(w[e]);
        csr_pair[p] = pr;
    }
}

__global__ void ones_kernel(const int* __restrict__ bi, float* __restrict__ m0) {
    int j = threadIdx.x;  // 256 threads
    m0[(size_t)bi[j] * BATCH + j] = 1.0f;
}

// ---------------- fused SpMM + polynomial accumulation ----------------
// One wave per destination node; lane owns 4 columns (float4).
__global__ void spmm_kernel(const float* __restrict__ min_, float* __restrict__ mout,
                            const int* __restrict__ rowStart, const int* __restrict__ counts,
                            const int2* __restrict__ csr_pair,
                            const float* __restrict__ coeffs, int k,
                            float* __restrict__ out, const int* __restrict__ bi) {
    int wave = threadIdx.x >> 6;
    int lane = threadIdx.x & 63;
    int node = blockIdx.x * 4 + wave;
    if (node >= N_NODES) return;
    int col0 = lane * 4;

    int start = rowStart[node];
    int len   = counts[node];

    float4 acc = make_float4(0.f, 0.f, 0.f, 0.f);
    for (int i = 0; i < len; ++i) {
        int2 pr = csr_pair[start + i];
        float w = __int_as_float(pr.y);
        const float4 v = *(const float4*)(min_ + (size_t)pr.x * BATCH + col0);
        acc.x += w * v.x;
        acc.y += w * v.y;
        acc.z += w * v.z;
        acc.w += w * v.w;
    }

    size_t base = (size_t)node * BATCH + col0;
    *(float4*)(mout + base) = acc;

    if (k == 1) {
        // out[t] = c[t][0]*onehot + c[t][1]*acc   (full write, kills poison)
        float oh0 = (bi[col0 + 0] == node) ? 1.0f : 0.0f;
        float oh1 = (bi[col0 + 1] == node) ? 1.0f : 0.0f;
        float oh2 = (bi[col0 + 2] == node) ? 1.0f : 0.0f;
        float oh3 = (bi[col0 + 3] == node) ? 1.0f : 0.0f;
        #pragma unroll
        for (int t = 0; t < NUM_TAU; ++t) {
            float c0 = coeffs[t * (ORDER + 1) + 0];
            float ck = coeffs[t * (ORDER + 1) + 1];
            float4 o;
            o.x = c0 * oh0 + ck * acc.x;
            o.y = c0 * oh1 + ck * acc.y;
            o.z = c0 * oh2 + ck * acc.z;
            o.w = c0 * oh3 + ck * acc.w;
            *(float4*)(out + (size_t)t * NB + base) = o;
        }
    } else {
        #pragma unroll
        for (int t = 0; t < NUM_TAU; ++t) {
            float ck = coeffs[t * (ORDER + 1) + k];
            float4 o = *(const float4*)(out + (size_t)t * NB + base);
            o.x += ck * acc.x;
            o.y += ck * acc.y;
            o.z += ck * acc.z;
            o.w += ck * acc.w;
            *(float4*)(out + (size_t)t * NB + base) = o;
        }
    }
}

extern "C" void kernel_launch(void* const* d_in, const int* in_sizes, int n_in,
                              void* d_out, int out_size, void* d_ws, size_t ws_size,
                              hipStream_t stream) {
    const float* coeffs = (const float*)d_in[0];
    const float* ew     = (const float*)d_in[1];
    const int*   src    = (const int*)d_in[2];
    const int*   dst    = (const int*)d_in[3];
    const int*   bi     = (const int*)d_in[4];   // int32 (JAX x64 disabled)
    const int E = in_sizes[1];

    float* out = (float*)d_out;

    // workspace layout (256B aligned)
    uintptr_t p = (uintptr_t)d_ws;
    auto align_up = [](uintptr_t v, uintptr_t a) { return (v + a - 1) & ~(a - 1); };
    int* counts      = (int*)p;                      p += (size_t)N_NODES * 4; p = align_up(p, 256);
    int* rowStart    = (int*)p;                      p += (size_t)N_NODES * 4; p = align_up(p, 256);
    int* cursor      = (int*)p;                      p += (size_t)N_NODES * 4; p = align_up(p, 256);
    int* totalCursor = (int*)p;                      p += 256;
    int2* csr_pair   = (int2*)p;                     p += (size_t)E * 8;       p = align_up(p, 256);
    float* mb0       = (float*)p;                    p += (size_t)NB * 4;      p = align_up(p, 256);
    float* mb1       = (float*)p;                    p += (size_t)NB * 4;

    hipMemsetAsync(counts, 0, (size_t)N_NODES * 4, stream);
    hipMemsetAsync(totalCursor, 0, 4, stream);
    hipMemsetAsync(mb0, 0, (size_t)NB * 4, stream);

    int eb = (E + 255) / 256;
    hist_kernel<<<eb, 256, 0, stream>>>(dst, counts, E);
    alloc_kernel<<<(N_NODES + 255) / 256, 256, 0, stream>>>(counts, rowStart, cursor, totalCursor);
    scatter_kernel<<<eb, 256, 0, stream>>>(src, dst, ew, cursor, csr_pair, E);
    ones_kernel<<<1, 256, 0, stream>>>(bi, mb0);

    float* cur = mb0;
    float* nxt = mb1;
    int grid = (N_NODES + 3) / 4;  // 4 nodes per 256-thread block
    for (int k = 1; k <= ORDER; ++k) {
        spmm_kernel<<<grid, 256, 0, stream>>>(cur, nxt, rowStart, counts, csr_pair,
                                              coeffs, k, out, bi);
        float* t = cur; cur = nxt; nxt = t;
    }
}

// Round 3
// 3733.031 us; speedup vs baseline: 1.2598x; 1.2598x over previous
//
#include <hip/hip_runtime.h>

#define N_NODES 100000
#define BATCH   256
#define NUM_TAU 4
#define ORDER   8
#define NB      ((size_t)N_NODES * BATCH)   // 25,600,000 elements per tau slice

// ---------------- CSR build ----------------

__global__ void hist_kernel(const int* __restrict__ dst, int* __restrict__ counts, int E) {
    int e = blockIdx.x * blockDim.x + threadIdx.x;
    if (e < E) atomicAdd(&counts[dst[e]], 1);
}

__global__ void alloc_kernel(const int* __restrict__ counts, int* __restrict__ rowStart,
                             int* __restrict__ cursor, int* __restrict__ totalCursor) {
    int n = blockIdx.x * blockDim.x + threadIdx.x;
    if (n < N_NODES) {
        int len = counts[n];
        int start = atomicAdd(totalCursor, len);
        rowStart[n] = start;
        cursor[n] = start;
    }
}

__global__ void scatter_kernel(const int* __restrict__ src, const int* __restrict__ dst,
                               const float* __restrict__ w, int* __restrict__ cursor,
                               int2* __restrict__ csr_pair, int E) {
    int e = blockIdx.x * blockDim.x + threadIdx.x;
    if (e < E) {
        int d = dst[e];
        int p = atomicAdd(&cursor[d], 1);
        int2 pr;
        pr.x = src[e];
        pr.y = __float_as_int(w[e]);
        csr_pair[p] = pr;
    }
}

// ---------------- sparse m1 = A @ onehot ----------------
// col_of_node[n] = first batch column j with bi[j]==n (linked via next_dup), else -1.
__global__ void colmap_kernel(const int* __restrict__ bi, int* __restrict__ col_of_node,
                              int* __restrict__ next_dup) {
    int j = threadIdx.x;  // 256
    int prev = atomicExch(&col_of_node[bi[j]], j);
    next_dup[j] = prev;
}

__global__ void m1_edges_kernel(const int* __restrict__ src, const int* __restrict__ dst,
                                const float* __restrict__ w,
                                const int* __restrict__ col_of_node,
                                const int* __restrict__ next_dup,
                                float* __restrict__ m1, int E) {
    int e = blockIdx.x * blockDim.x + threadIdx.x;
    if (e >= E) return;
    int j = col_of_node[src[e]];
    if (j < 0) return;
    float we = w[e];
    size_t rb = (size_t)dst[e] * BATCH;
    while (j >= 0) {
        atomicAdd(&m1[rb + j], we);
        j = next_dup[j];
    }
}

// ---------------- plain SpMM: mout = A @ min ----------------
// One wave per destination node; lane owns 4 columns (float4).
__global__ void spmm_plain(const float* __restrict__ min_, float* __restrict__ mout,
                           const int* __restrict__ rowStart, const int* __restrict__ counts,
                           const int2* __restrict__ csr_pair) {
    int wave = threadIdx.x >> 6;
    int lane = threadIdx.x & 63;
    int node = blockIdx.x * 4 + wave;
    if (node >= N_NODES) return;
    int col0 = lane * 4;

    int start = rowStart[node];
    int len   = counts[node];

    float4 acc = make_float4(0.f, 0.f, 0.f, 0.f);
    for (int i = 0; i < len; ++i) {
        int2 pr = csr_pair[start + i];
        float w = __int_as_float(pr.y);
        const float4 v = *(const float4*)(min_ + (size_t)pr.x * BATCH + col0);
        acc.x += w * v.x;
        acc.y += w * v.y;
        acc.z += w * v.z;
        acc.w += w * v.w;
    }
    *(float4*)(mout + (size_t)node * BATCH + col0) = acc;
}

// ---------------- final combine: out[t] = c[t,0]*onehot + sum_k c[t,k]*m_k ----------------
// m1..m4 in ws (contiguous), m5..m8 live in the out buffer slices (read before write).
__global__ void combine_kernel(float* __restrict__ out, const float* __restrict__ m14,
                               const float* __restrict__ coeffs, const int* __restrict__ bi) {
    size_t tid = (size_t)blockIdx.x * blockDim.x + threadIdx.x;
    size_t base = tid * 4;
    if (base >= NB) return;
    int node = (int)(base >> 8);
    int j0   = (int)(base & 255);

    float4 p[ORDER];
    #pragma unroll
    for (int k = 1; k <= 4; ++k)
        p[k - 1] = *(const float4*)(m14 + (size_t)(k - 1) * NB + base);
    #pragma unroll
    for (int k = 5; k <= 8; ++k)
        p[k - 1] = *(const float4*)(out + (size_t)(k - 5) * NB + base);

    float oh[4];
    #pragma unroll
    for (int i = 0; i < 4; ++i) oh[i] = (bi[j0 + i] == node) ? 1.0f : 0.0f;

    #pragma unroll
    for (int t = 0; t < NUM_TAU; ++t) {
        float c0 = coeffs[t * (ORDER + 1)];
        float4 o = make_float4(c0 * oh[0], c0 * oh[1], c0 * oh[2], c0 * oh[3]);
        #pragma unroll
        for (int k = 1; k <= ORDER; ++k) {
            float c = coeffs[t * (ORDER + 1) + k];
            o.x += c * p[k - 1].x;
            o.y += c * p[k - 1].y;
            o.z += c * p[k - 1].z;
            o.w += c * p[k - 1].w;
        }
        *(float4*)(out + (size_t)t * NB + base) = o;
    }
}

// ---------------- fallback (round-2 proven path) ----------------

__global__ void ones_kernel(const int* __restrict__ bi, float* __restrict__ m0) {
    int j = threadIdx.x;  // 256
    m0[(size_t)bi[j] * BATCH + j] = 1.0f;
}

__global__ void spmm_fused(const float* __restrict__ min_, float* __restrict__ mout,
                           const int* __restrict__ rowStart, const int* __restrict__ counts,
                           const int2* __restrict__ csr_pair,
                           const float* __restrict__ coeffs, int k,
                           float* __restrict__ out, const int* __restrict__ bi) {
    int wave = threadIdx.x >> 6;
    int lane = threadIdx.x & 63;
    int node = blockIdx.x * 4 + wave;
    if (node >= N_NODES) return;
    int col0 = lane * 4;
    int start = rowStart[node];
    int len   = counts[node];
    float4 acc = make_float4(0.f, 0.f, 0.f, 0.f);
    for (int i = 0; i < len; ++i) {
        int2 pr = csr_pair[start + i];
        float w = __int_as_float(pr.y);
        const float4 v = *(const float4*)(min_ + (size_t)pr.x * BATCH + col0);
        acc.x += w * v.x; acc.y += w * v.y; acc.z += w * v.z; acc.w += w * v.w;
    }
    size_t base = (size_t)node * BATCH + col0;
    *(float4*)(mout + base) = acc;
    if (k == 1) {
        float oh0 = (bi[col0 + 0] == node) ? 1.0f : 0.0f;
        float oh1 = (bi[col0 + 1] == node) ? 1.0f : 0.0f;
        float oh2 = (bi[col0 + 2] == node) ? 1.0f : 0.0f;
        float oh3 = (bi[col0 + 3] == node) ? 1.0f : 0.0f;
        #pragma unroll
        for (int t = 0; t < NUM_TAU; ++t) {
            float c0 = coeffs[t * (ORDER + 1) + 0];
            float ck = coeffs[t * (ORDER + 1) + 1];
            float4 o;
            o.x = c0 * oh0 + ck * acc.x;
            o.y = c0 * oh1 + ck * acc.y;
            o.z = c0 * oh2 + ck * acc.z;
            o.w = c0 * oh3 + ck * acc.w;
            *(float4*)(out + (size_t)t * NB + base) = o;
        }
    } else {
        #pragma unroll
        for (int t = 0; t < NUM_TAU; ++t) {
            float ck = coeffs[t * (ORDER + 1) + k];
            float4 o = *(const float4*)(out + (size_t)t * NB + base);
            o.x += ck * acc.x; o.y += ck * acc.y; o.z += ck * acc.z; o.w += ck * acc.w;
            *(float4*)(out + (size_t)t * NB + base) = o;
        }
    }
}

extern "C" void kernel_launch(void* const* d_in, const int* in_sizes, int n_in,
                              void* d_out, int out_size, void* d_ws, size_t ws_size,
                              hipStream_t stream) {
    const float* coeffs = (const float*)d_in[0];
    const float* ew     = (const float*)d_in[1];
    const int*   src    = (const int*)d_in[2];
    const int*   dst    = (const int*)d_in[3];
    const int*   bi     = (const int*)d_in[4];   // int32 on device (JAX x64 disabled)
    const int E = in_sizes[1];

    float* out = (float*)d_out;

    auto align_up = [](uintptr_t v, uintptr_t a) { return (v + a - 1) & ~(a - 1); };

    // common small buffers
    uintptr_t p0 = (uintptr_t)d_ws;
    int* counts      = (int*)p0;  p0 += (size_t)N_NODES * 4;  p0 = align_up(p0, 256);
    int* rowStart    = (int*)p0;  p0 += (size_t)N_NODES * 4;  p0 = align_up(p0, 256);
    int* cursor      = (int*)p0;  p0 += (size_t)N_NODES * 4;  p0 = align_up(p0, 256);
    int* totalCursor = (int*)p0;  p0 += 256;
    int* col_of_node = (int*)p0;  p0 += (size_t)N_NODES * 4;  p0 = align_up(p0, 256);
    int* next_dup    = (int*)p0;  p0 += 1024;                 p0 = align_up(p0, 256);
    int2* csr_pair   = (int2*)p0; p0 += (size_t)E * 8;        p0 = align_up(p0, 256);
    float* big       = (float*)p0;  // rest of ws
    size_t big_bytes = ((uintptr_t)d_ws + ws_size > p0) ? ((uintptr_t)d_ws + ws_size - p0) : 0;

    int eb = (E + 255) / 256;
    int nodeGrid = (N_NODES + 3) / 4;  // 4 waves (nodes) per 256-thread block

    hipMemsetAsync(counts, 0, (size_t)N_NODES * 4, stream);
    hipMemsetAsync(totalCursor, 0, 4, stream);

    hist_kernel<<<eb, 256, 0, stream>>>(dst, counts, E);
    alloc_kernel<<<(N_NODES + 255) / 256, 256, 0, stream>>>(counts, rowStart, cursor, totalCursor);
    scatter_kernel<<<eb, 256, 0, stream>>>(src, dst, ew, cursor, csr_pair, E);

    if (big_bytes >= 4 * NB * 4) {
        // ---- scheme A: store m1..m4 in ws, m5..m8 in out; one final combine ----
        float* mpow[ORDER + 1];
        for (int k = 1; k <= 4; ++k) mpow[k] = big + (size_t)(k - 1) * NB;
        for (int k = 5; k <= 8; ++k) mpow[k] = out + (size_t)(k - 5) * NB;

        hipMemsetAsync(col_of_node, 0xFF, (size_t)N_NODES * 4, stream);  // -1
        hipMemsetAsync(mpow[1], 0, NB * 4, stream);
        colmap_kernel<<<1, 256, 0, stream>>>(bi, col_of_node, next_dup);
        m1_edges_kernel<<<eb, 256, 0, stream>>>(src, dst, ew, col_of_node, next_dup,
                                                mpow[1], E);
        for (int k = 2; k <= ORDER; ++k) {
            spmm_plain<<<nodeGrid, 256, 0, stream>>>(mpow[k - 1], mpow[k],
                                                     rowStart, counts, csr_pair);
        }
        int cgrid = (int)((NB / 4 + 255) / 256);
        combine_kernel<<<cgrid, 256, 0, stream>>>(out, big, coeffs, bi);
    } else {
        // ---- fallback: round-2 fused RMW path (needs 2*NB floats) ----
        float* mb0 = big;
        float* mb1 = big + NB;
        hipMemsetAsync(mb0, 0, NB * 4, stream);
        ones_kernel<<<1, 256, 0, stream>>>(bi, mb0);
        float* cur = mb0; float* nxt = mb1;
        for (int k = 1; k <= ORDER; ++k) {
            spmm_fused<<<nodeGrid, 256, 0, stream>>>(cur, nxt, rowStart, counts, csr_pair,
                                                     coeffs, k, out, bi);
            float* t = cur; cur = nxt; nxt = t;
        }
    }
}

// Round 4
// 3652.859 us; speedup vs baseline: 1.2875x; 1.0219x over previous
//
#include <hip/hip_runtime.h>

#define N_NODES 100000
#define BATCH   256
#define NUM_TAU 4
#define ORDER   8
#define NB      ((size_t)N_NODES * BATCH)   // 25,600,000 elements per tau slice

// ---------------- CSR build ----------------

__global__ void hist_kernel(const int* __restrict__ dst, int* __restrict__ counts, int E) {
    int e = blockIdx.x * blockDim.x + threadIdx.x;
    if (e < E) atomicAdd(&counts[dst[e]], 1);
}

__global__ void alloc_kernel(const int* __restrict__ counts, int* __restrict__ rowStart,
                             int* __restrict__ cursor, int* __restrict__ totalCursor) {
    int n = blockIdx.x * blockDim.x + threadIdx.x;
    if (n < N_NODES) {
        int len = counts[n];
        int start = atomicAdd(totalCursor, len);
        rowStart[n] = start;
        cursor[n] = start;
    }
}

__global__ void scatter_kernel(const int* __restrict__ src, const int* __restrict__ dst,
                               const float* __restrict__ w, int* __restrict__ cursor,
                               int2* __restrict__ csr_pair, int E) {
    int e = blockIdx.x * blockDim.x + threadIdx.x;
    if (e < E) {
        int d = dst[e];
        int p = atomicAdd(&cursor[d], 1);
        int2 pr;
        pr.x = src[e];
        pr.y = __float_as_int(w[e]);
        csr_pair[p] = pr;
    }
}

// ---------------- sparse m1 = A @ onehot ----------------

__global__ void colmap_kernel(const int* __restrict__ bi, int* __restrict__ col_of_node,
                              int* __restrict__ next_dup) {
    int j = threadIdx.x;  // 256
    int prev = atomicExch(&col_of_node[bi[j]], j);
    next_dup[j] = prev;
}

__global__ void m1_edges_kernel(const int* __restrict__ src, const int* __restrict__ dst,
                                const float* __restrict__ w,
                                const int* __restrict__ col_of_node,
                                const int* __restrict__ next_dup,
                                float* __restrict__ m1, int E) {
    int e = blockIdx.x * blockDim.x + threadIdx.x;
    if (e >= E) return;
    int j = col_of_node[src[e]];
    if (j < 0) return;
    float we = w[e];
    size_t rb = (size_t)dst[e] * BATCH;
    while (j >= 0) {
        atomicAdd(&m1[rb + j], we);
        j = next_dup[j];
    }
}

// ---------------- half-width SpMM: 128 columns, lane owns float2 ----------------
// One wave per destination node; 8-deep software pipeline on the gather.
__global__ void spmm_half(const float* __restrict__ min_, float* __restrict__ mout,
                          const int* __restrict__ rowStart, const int* __restrict__ counts,
                          const int2* __restrict__ csr_pair, int colOff) {
    int wave = threadIdx.x >> 6;
    int lane = threadIdx.x & 63;
    int node = blockIdx.x * 4 + wave;
    if (node >= N_NODES) return;
    int c = colOff + lane * 2;

    int start = rowStart[node];
    int len   = counts[node];

    float2 acc = make_float2(0.f, 0.f);
    int i = 0;
    for (; i + 8 <= len; i += 8) {
        int2 pr[8];
        #pragma unroll
        for (int u = 0; u < 8; ++u) pr[u] = csr_pair[start + i + u];
        float2 v[8];
        #pragma unroll
        for (int u = 0; u < 8; ++u)
            v[u] = *(const float2*)(min_ + (size_t)pr[u].x * BATCH + c);
        #pragma unroll
        for (int u = 0; u < 8; ++u) {
            float w = __int_as_float(pr[u].y);
            acc.x += w * v[u].x;
            acc.y += w * v[u].y;
        }
    }
    for (; i < len; ++i) {
        int2 pr = csr_pair[start + i];
        float w = __int_as_float(pr.y);
        float2 v = *(const float2*)(min_ + (size_t)pr.x * BATCH + c);
        acc.x += w * v.x;
        acc.y += w * v.y;
    }
    *(float2*)(mout + (size_t)node * BATCH + c) = acc;
}

// ---------------- final combine: out[t] = c[t,0]*onehot + sum_k c[t,k]*m_k ----------------
__global__ void combine_kernel(float* __restrict__ out, const float* __restrict__ m14,
                               const float* __restrict__ coeffs, const int* __restrict__ bi) {
    size_t tid = (size_t)blockIdx.x * blockDim.x + threadIdx.x;
    size_t base = tid * 4;
    if (base >= NB) return;
    int node = (int)(base >> 8);
    int j0   = (int)(base & 255);

    float4 p[ORDER];
    #pragma unroll
    for (int k = 1; k <= 4; ++k)
        p[k - 1] = *(const float4*)(m14 + (size_t)(k - 1) * NB + base);
    #pragma unroll
    for (int k = 5; k <= 8; ++k)
        p[k - 1] = *(const float4*)(out + (size_t)(k - 5) * NB + base);

    float oh[4];
    #pragma unroll
    for (int i = 0; i < 4; ++i) oh[i] = (bi[j0 + i] == node) ? 1.0f : 0.0f;

    #pragma unroll
    for (int t = 0; t < NUM_TAU; ++t) {
        float c0 = coeffs[t * (ORDER + 1)];
        float4 o = make_float4(c0 * oh[0], c0 * oh[1], c0 * oh[2], c0 * oh[3]);
        #pragma unroll
        for (int k = 1; k <= ORDER; ++k) {
            float c = coeffs[t * (ORDER + 1) + k];
            o.x += c * p[k - 1].x;
            o.y += c * p[k - 1].y;
            o.z += c * p[k - 1].z;
            o.w += c * p[k - 1].w;
        }
        *(float4*)(out + (size_t)t * NB + base) = o;
    }
}

// ---------------- fallback (round-2 proven path) ----------------

__global__ void ones_kernel(const int* __restrict__ bi, float* __restrict__ m0) {
    int j = threadIdx.x;  // 256
    m0[(size_t)bi[j] * BATCH + j] = 1.0f;
}

__global__ void spmm_fused(const float* __restrict__ min_, float* __restrict__ mout,
                           const int* __restrict__ rowStart, const int* __restrict__ counts,
                           const int2* __restrict__ csr_pair,
                           const float* __restrict__ coeffs, int k,
                           float* __restrict__ out, const int* __restrict__ bi) {
    int wave = threadIdx.x >> 6;
    int lane = threadIdx.x & 63;
    int node = blockIdx.x * 4 + wave;
    if (node >= N_NODES) return;
    int col0 = lane * 4;
    int start = rowStart[node];
    int len   = counts[node];
    float4 acc = make_float4(0.f, 0.f, 0.f, 0.f);
    for (int i = 0; i < len; ++i) {
        int2 pr = csr_pair[start + i];
        float w = __int_as_float(pr.y);
        const float4 v = *(const float4*)(min_ + (size_t)pr.x * BATCH + col0);
        acc.x += w * v.x; acc.y += w * v.y; acc.z += w * v.z; acc.w += w * v.w;
    }
    size_t base = (size_t)node * BATCH + col0;
    *(float4*)(mout + base) = acc;
    if (k == 1) {
        float oh0 = (bi[col0 + 0] == node) ? 1.0f : 0.0f;
        float oh1 = (bi[col0 + 1] == node) ? 1.0f : 0.0f;
        float oh2 = (bi[col0 + 2] == node) ? 1.0f : 0.0f;
        float oh3 = (bi[col0 + 3] == node) ? 1.0f : 0.0f;
        #pragma unroll
        for (int t = 0; t < NUM_TAU; ++t) {
            float c0 = coeffs[t * (ORDER + 1) + 0];
            float ck = coeffs[t * (ORDER + 1) + 1];
            float4 o;
            o.x = c0 * oh0 + ck * acc.x;
            o.y = c0 * oh1 + ck * acc.y;
            o.z = c0 * oh2 + ck * acc.z;
            o.w = c0 * oh3 + ck * acc.w;
            *(float4*)(out + (size_t)t * NB + base) = o;
        }
    } else {
        #pragma unroll
        for (int t = 0; t < NUM_TAU; ++t) {
            float ck = coeffs[t * (ORDER + 1) + k];
            float4 o = *(const float4*)(out + (size_t)t * NB + base);
            o.x += ck * acc.x; o.y += ck * acc.y; o.z += ck * acc.z; o.w += ck * acc.w;
            *(float4*)(out + (size_t)t * NB + base) = o;
        }
    }
}

extern "C" void kernel_launch(void* const* d_in, const int* in_sizes, int n_in,
                              void* d_out, int out_size, void* d_ws, size_t ws_size,
                              hipStream_t stream) {
    const float* coeffs = (const float*)d_in[0];
    const float* ew     = (const float*)d_in[1];
    const int*   src    = (const int*)d_in[2];
    const int*   dst    = (const int*)d_in[3];
    const int*   bi     = (const int*)d_in[4];   // int32 on device (JAX x64 disabled)
    const int E = in_sizes[1];

    float* out = (float*)d_out;

    auto align_up = [](uintptr_t v, uintptr_t a) { return (v + a - 1) & ~(a - 1); };

    uintptr_t p0 = (uintptr_t)d_ws;
    int* counts      = (int*)p0;  p0 += (size_t)N_NODES * 4;  p0 = align_up(p0, 256);
    int* rowStart    = (int*)p0;  p0 += (size_t)N_NODES * 4;  p0 = align_up(p0, 256);
    int* cursor      = (int*)p0;  p0 += (size_t)N_NODES * 4;  p0 = align_up(p0, 256);
    int* totalCursor = (int*)p0;  p0 += 256;
    int* col_of_node = (int*)p0;  p0 += (size_t)N_NODES * 4;  p0 = align_up(p0, 256);
    int* next_dup    = (int*)p0;  p0 += 1024;                 p0 = align_up(p0, 256);
    int2* csr_pair   = (int2*)p0; p0 += (size_t)E * 8;        p0 = align_up(p0, 256);
    float* big       = (float*)p0;  // rest of ws
    size_t big_bytes = ((uintptr_t)d_ws + ws_size > p0) ? ((uintptr_t)d_ws + ws_size - p0) : 0;

    int eb = (E + 255) / 256;
    int nodeGrid = (N_NODES + 3) / 4;  // 4 waves (nodes) per 256-thread block

    hipMemsetAsync(counts, 0, (size_t)N_NODES * 4, stream);
    hipMemsetAsync(totalCursor, 0, 4, stream);

    hist_kernel<<<eb, 256, 0, stream>>>(dst, counts, E);
    alloc_kernel<<<(N_NODES + 255) / 256, 256, 0, stream>>>(counts, rowStart, cursor, totalCursor);
    scatter_kernel<<<eb, 256, 0, stream>>>(src, dst, ew, cursor, csr_pair, E);

    if (big_bytes >= 4 * NB * 4) {
        // ---- scheme A: m1..m4 in ws, m5..m8 in out; column-halved k-chain ----
        float* mpow[ORDER + 1];
        for (int k = 1; k <= 4; ++k) mpow[k] = big + (size_t)(k - 1) * NB;
        for (int k = 5; k <= 8; ++k) mpow[k] = out + (size_t)(k - 5) * NB;

        hipMemsetAsync(col_of_node, 0xFF, (size_t)N_NODES * 4, stream);  // -1
        hipMemsetAsync(mpow[1], 0, NB * 4, stream);
        colmap_kernel<<<1, 256, 0, stream>>>(bi, col_of_node, next_dup);
        m1_edges_kernel<<<eb, 256, 0, stream>>>(src, dst, ew, col_of_node, next_dup,
                                                mpow[1], E);
        // independent column halves: keep the 128-MB working set LLC-resident
        for (int h = 0; h < 2; ++h) {
            int colOff = h * 128;
            for (int k = 2; k <= ORDER; ++k) {
                spmm_half<<<nodeGrid, 256, 0, stream>>>(mpow[k - 1], mpow[k],
                                                        rowStart, counts, csr_pair, colOff);
            }
        }
        int cgrid = (int)((NB / 4 + 255) / 256);
        combine_kernel<<<cgrid, 256, 0, stream>>>(out, big, coeffs, bi);
    } else {
        // ---- fallback: round-2 fused RMW path (needs 2*NB floats) ----
        float* mb0 = big;
        float* mb1 = big + NB;
        hipMemsetAsync(mb0, 0, NB * 4, stream);
        ones_kernel<<<1, 256, 0, stream>>>(bi, mb0);
        float* cur = mb0; float* nxt = mb1;
        for (int k = 1; k <= ORDER; ++k) {
            spmm_fused<<<nodeGrid, 256, 0, stream>>>(cur, nxt, rowStart, counts, csr_pair,
                                                     coeffs, k, out, bi);
            float* t = cur; cur = nxt; nxt = t;
        }
    }
}

// Round 5
// 2075.936 us; speedup vs baseline: 2.2655x; 1.7596x over previous
//
#include <hip/hip_runtime.h>

#define N_NODES 100000
#define BATCH   256
#define NUM_TAU 4
#define ORDER   8
#define NB      ((size_t)N_NODES * BATCH)   // 25,600,000 elements per tau slice

__device__ __forceinline__ unsigned short f2bf(float f) {
    unsigned int u = __float_as_uint(f);
    u += 0x7FFFu + ((u >> 16) & 1u);   // round-to-nearest-even
    return (unsigned short)(u >> 16);
}
__device__ __forceinline__ float bf2f(unsigned short h) {
    return __uint_as_float((unsigned int)h << 16);
}

// ---------------- CSR build ----------------

__global__ void hist_kernel(const int* __restrict__ dst, int* __restrict__ counts, int E) {
    int e = blockIdx.x * blockDim.x + threadIdx.x;
    if (e < E) atomicAdd(&counts[dst[e]], 1);
}

__global__ void alloc_kernel(const int* __restrict__ counts, int* __restrict__ rowStart,
                             int* __restrict__ cursor, int* __restrict__ totalCursor) {
    int n = blockIdx.x * blockDim.x + threadIdx.x;
    if (n < N_NODES) {
        int len = counts[n];
        int start = atomicAdd(totalCursor, len);
        rowStart[n] = start;
        cursor[n] = start;
    }
}

__global__ void scatter_kernel(const int* __restrict__ src, const int* __restrict__ dst,
                               const float* __restrict__ w, int* __restrict__ cursor,
                               int2* __restrict__ csr_pair, int E) {
    int e = blockIdx.x * blockDim.x + threadIdx.x;
    if (e < E) {
        int d = dst[e];
        int p = atomicAdd(&cursor[d], 1);
        int2 pr;
        pr.x = src[e];
        pr.y = __float_as_int(w[e]);
        csr_pair[p] = pr;
    }
}

// ---------------- sparse m1 = A @ onehot  (m1 fp32, lives in out slice 0) ----------------

__global__ void colmap_kernel(const int* __restrict__ bi, int* __restrict__ col_of_node,
                              int* __restrict__ next_dup) {
    int j = threadIdx.x;  // 256
    int prev = atomicExch(&col_of_node[bi[j]], j);
    next_dup[j] = prev;
}

__global__ void m1_edges_kernel(const int* __restrict__ src, const int* __restrict__ dst,
                                const float* __restrict__ w,
                                const int* __restrict__ col_of_node,
                                const int* __restrict__ next_dup,
                                float* __restrict__ m1, int* __restrict__ flag, int E) {
    int e = blockIdx.x * blockDim.x + threadIdx.x;
    if (e >= E) return;
    int j = col_of_node[src[e]];
    if (j < 0) return;
    float we = w[e];
    int d = dst[e];
    flag[d] = 1;
    size_t rb = (size_t)d * BATCH;
    while (j >= 0) {
        atomicAdd(&m1[rb + j], we);
        j = next_dup[j];
    }
}

// ---------------- k=2: fp32 m1 (sparse rows, flag-skipped) -> bf16 m2 ----------------
__global__ void spmm_k2(const float* __restrict__ m1, unsigned short* __restrict__ m2,
                        const int* __restrict__ rowStart, const int* __restrict__ counts,
                        const int2* __restrict__ csr_pair, const int* __restrict__ flag) {
    int wave = threadIdx.x >> 6;
    int lane = threadIdx.x & 63;
    int node = blockIdx.x * 4 + wave;
    if (node >= N_NODES) return;
    int col0 = lane * 4;

    int start = rowStart[node];
    int len   = counts[node];

    float4 acc = make_float4(0.f, 0.f, 0.f, 0.f);
    for (int i = 0; i < len; ++i) {
        int2 pr = csr_pair[start + i];
        if (flag[pr.x]) {
            float w = __int_as_float(pr.y);
            float4 v = *(const float4*)(m1 + (size_t)pr.x * BATCH + col0);
            acc.x += w * v.x; acc.y += w * v.y; acc.z += w * v.z; acc.w += w * v.w;
        }
    }
    ushort4 o;
    o.x = f2bf(acc.x); o.y = f2bf(acc.y); o.z = f2bf(acc.z); o.w = f2bf(acc.w);
    *(ushort4*)(m2 + (size_t)node * BATCH + col0) = o;
}

// ---------------- bf16 -> bf16 SpMM, 8-deep gather pipeline ----------------
__global__ void spmm_bf(const unsigned short* __restrict__ min_, unsigned short* __restrict__ mout,
                        const int* __restrict__ rowStart, const int* __restrict__ counts,
                        const int2* __restrict__ csr_pair) {
    int wave = threadIdx.x >> 6;
    int lane = threadIdx.x & 63;
    int node = blockIdx.x * 4 + wave;
    if (node >= N_NODES) return;
    int col0 = lane * 4;

    int start = rowStart[node];
    int len   = counts[node];

    float4 acc = make_float4(0.f, 0.f, 0.f, 0.f);
    int i = 0;
    for (; i + 8 <= len; i += 8) {
        int2 pr[8];
        #pragma unroll
        for (int u = 0; u < 8; ++u) pr[u] = csr_pair[start + i + u];
        ushort4 v[8];
        #pragma unroll
        for (int u = 0; u < 8; ++u)
            v[u] = *(const ushort4*)(min_ + (size_t)pr[u].x * BATCH + col0);
        #pragma unroll
        for (int u = 0; u < 8; ++u) {
            float w = __int_as_float(pr[u].y);
            acc.x += w * bf2f(v[u].x);
            acc.y += w * bf2f(v[u].y);
            acc.z += w * bf2f(v[u].z);
            acc.w += w * bf2f(v[u].w);
        }
    }
    for (; i < len; ++i) {
        int2 pr = csr_pair[start + i];
        float w = __int_as_float(pr.y);
        ushort4 v = *(const ushort4*)(min_ + (size_t)pr.x * BATCH + col0);
        acc.x += w * bf2f(v.x);
        acc.y += w * bf2f(v.y);
        acc.z += w * bf2f(v.z);
        acc.w += w * bf2f(v.w);
    }
    ushort4 o;
    o.x = f2bf(acc.x); o.y = f2bf(acc.y); o.z = f2bf(acc.z); o.w = f2bf(acc.w);
    *(ushort4*)(mout + (size_t)node * BATCH + col0) = o;
}

// ---------------- combine: out[t] = c[t,0]*onehot + c[t,1]*m1 + sum_{k>=2} c[t,k]*m_k ----------------
// m1 fp32 in out slice 0 (read-then-write in-place); m2..m8 bf16 in ws.
__global__ void combine_bf(float* __restrict__ out, const unsigned short* __restrict__ m28,
                           const float* __restrict__ coeffs, const int* __restrict__ bi) {
    size_t tid = (size_t)blockIdx.x * blockDim.x + threadIdx.x;
    size_t base = tid * 4;
    if (base >= NB) return;
    int node = (int)(base >> 8);
    int j0   = (int)(base & 255);

    float4 p[ORDER];
    p[0] = *(const float4*)(out + base);  // m1 (slice 0, in-place)
    #pragma unroll
    for (int k = 2; k <= ORDER; ++k) {
        ushort4 v = *(const ushort4*)(m28 + (size_t)(k - 2) * NB + base);
        p[k - 1] = make_float4(bf2f(v.x), bf2f(v.y), bf2f(v.z), bf2f(v.w));
    }

    float oh[4];
    #pragma unroll
    for (int i = 0; i < 4; ++i) oh[i] = (bi[j0 + i] == node) ? 1.0f : 0.0f;

    #pragma unroll
    for (int t = 0; t < NUM_TAU; ++t) {
        float c0 = coeffs[t * (ORDER + 1)];
        float4 o = make_float4(c0 * oh[0], c0 * oh[1], c0 * oh[2], c0 * oh[3]);
        #pragma unroll
        for (int k = 1; k <= ORDER; ++k) {
            float c = coeffs[t * (ORDER + 1) + k];
            o.x += c * p[k - 1].x;
            o.y += c * p[k - 1].y;
            o.z += c * p[k - 1].z;
            o.w += c * p[k - 1].w;
        }
        *(float4*)(out + (size_t)t * NB + base) = o;
    }
}

// ---------------- fallback scheme B (round-3/4 proven fp32 path) ----------------

__global__ void spmm_half(const float* __restrict__ min_, float* __restrict__ mout,
                          const int* __restrict__ rowStart, const int* __restrict__ counts,
                          const int2* __restrict__ csr_pair, int colOff) {
    int wave = threadIdx.x >> 6;
    int lane = threadIdx.x & 63;
    int node = blockIdx.x * 4 + wave;
    if (node >= N_NODES) return;
    int c = colOff + lane * 2;
    int start = rowStart[node];
    int len   = counts[node];
    float2 acc = make_float2(0.f, 0.f);
    int i = 0;
    for (; i + 8 <= len; i += 8) {
        int2 pr[8];
        #pragma unroll
        for (int u = 0; u < 8; ++u) pr[u] = csr_pair[start + i + u];
        float2 v[8];
        #pragma unroll
        for (int u = 0; u < 8; ++u)
            v[u] = *(const float2*)(min_ + (size_t)pr[u].x * BATCH + c);
        #pragma unroll
        for (int u = 0; u < 8; ++u) {
            float w = __int_as_float(pr[u].y);
            acc.x += w * v[u].x;
            acc.y += w * v[u].y;
        }
    }
    for (; i < len; ++i) {
        int2 pr = csr_pair[start + i];
        float w = __int_as_float(pr.y);
        float2 v = *(const float2*)(min_ + (size_t)pr.x * BATCH + c);
        acc.x += w * v.x;
        acc.y += w * v.y;
    }
    *(float2*)(mout + (size_t)node * BATCH + c) = acc;
}

__global__ void combine_kernel(float* __restrict__ out, const float* __restrict__ m14,
                               const float* __restrict__ coeffs, const int* __restrict__ bi) {
    size_t tid = (size_t)blockIdx.x * blockDim.x + threadIdx.x;
    size_t base = tid * 4;
    if (base >= NB) return;
    int node = (int)(base >> 8);
    int j0   = (int)(base & 255);
    float4 p[ORDER];
    #pragma unroll
    for (int k = 1; k <= 4; ++k)
        p[k - 1] = *(const float4*)(m14 + (size_t)(k - 1) * NB + base);
    #pragma unroll
    for (int k = 5; k <= 8; ++k)
        p[k - 1] = *(const float4*)(out + (size_t)(k - 5) * NB + base);
    float oh[4];
    #pragma unroll
    for (int i = 0; i < 4; ++i) oh[i] = (bi[j0 + i] == node) ? 1.0f : 0.0f;
    #pragma unroll
    for (int t = 0; t < NUM_TAU; ++t) {
        float c0 = coeffs[t * (ORDER + 1)];
        float4 o = make_float4(c0 * oh[0], c0 * oh[1], c0 * oh[2], c0 * oh[3]);
        #pragma unroll
        for (int k = 1; k <= ORDER; ++k) {
            float c = coeffs[t * (ORDER + 1) + k];
            o.x += c * p[k - 1].x;
            o.y += c * p[k - 1].y;
            o.z += c * p[k - 1].z;
            o.w += c * p[k - 1].w;
        }
        *(float4*)(out + (size_t)t * NB + base) = o;
    }
}

extern "C" void kernel_launch(void* const* d_in, const int* in_sizes, int n_in,
                              void* d_out, int out_size, void* d_ws, size_t ws_size,
                              hipStream_t stream) {
    const float* coeffs = (const float*)d_in[0];
    const float* ew     = (const float*)d_in[1];
    const int*   src    = (const int*)d_in[2];
    const int*   dst    = (const int*)d_in[3];
    const int*   bi     = (const int*)d_in[4];   // int32 on device (JAX x64 disabled)
    const int E = in_sizes[1];

    float* out = (float*)d_out;

    auto align_up = [](uintptr_t v, uintptr_t a) { return (v + a - 1) & ~(a - 1); };

    uintptr_t p0 = (uintptr_t)d_ws;
    int* counts      = (int*)p0;  p0 += (size_t)N_NODES * 4;  p0 = align_up(p0, 256);
    int* rowStart    = (int*)p0;  p0 += (size_t)N_NODES * 4;  p0 = align_up(p0, 256);
    int* cursor      = (int*)p0;  p0 += (size_t)N_NODES * 4;  p0 = align_up(p0, 256);
    int* totalCursor = (int*)p0;  p0 += 256;
    int* col_of_node = (int*)p0;  p0 += (size_t)N_NODES * 4;  p0 = align_up(p0, 256);
    int* next_dup    = (int*)p0;  p0 += 1024;                 p0 = align_up(p0, 256);
    int* flag        = (int*)p0;  p0 += (size_t)N_NODES * 4;  p0 = align_up(p0, 256);
    int2* csr_pair   = (int2*)p0; p0 += (size_t)E * 8;        p0 = align_up(p0, 256);
    void* big        = (void*)p0;
    size_t big_bytes = ((uintptr_t)d_ws + ws_size > p0) ? ((uintptr_t)d_ws + ws_size - p0) : 0;

    int eb = (E + 255) / 256;
    int nodeGrid = (N_NODES + 3) / 4;  // 4 waves (nodes) per 256-thread block
    int cgrid = (int)((NB / 4 + 255) / 256);

    hipMemsetAsync(counts, 0, (size_t)N_NODES * 4, stream);
    hipMemsetAsync(totalCursor, 0, 4, stream);

    hist_kernel<<<eb, 256, 0, stream>>>(dst, counts, E);
    alloc_kernel<<<(N_NODES + 255) / 256, 256, 0, stream>>>(counts, rowStart, cursor, totalCursor);
    scatter_kernel<<<eb, 256, 0, stream>>>(src, dst, ew, cursor, csr_pair, E);

    if (big_bytes >= 7 * NB * 2) {
        // ---- scheme A (bf16 chain): m1 fp32 in out slice 0, m2..m8 bf16 in ws ----
        unsigned short* m28 = (unsigned short*)big;
        float* m1 = out;  // slice 0

        hipMemsetAsync(col_of_node, 0xFF, (size_t)N_NODES * 4, stream);  // -1
        hipMemsetAsync(flag, 0, (size_t)N_NODES * 4, stream);
        hipMemsetAsync(m1, 0, NB * 4, stream);

        colmap_kernel<<<1, 256, 0, stream>>>(bi, col_of_node, next_dup);
        m1_edges_kernel<<<eb, 256, 0, stream>>>(src, dst, ew, col_of_node, next_dup,
                                                m1, flag, E);
        spmm_k2<<<nodeGrid, 256, 0, stream>>>(m1, m28, rowStart, counts, csr_pair, flag);
        for (int k = 3; k <= ORDER; ++k) {
            spmm_bf<<<nodeGrid, 256, 0, stream>>>(m28 + (size_t)(k - 3) * NB,
                                                  m28 + (size_t)(k - 2) * NB,
                                                  rowStart, counts, csr_pair);
        }
        combine_bf<<<cgrid, 256, 0, stream>>>(out, m28, coeffs, bi);
    } else {
        // ---- scheme B (fp32): m1..m4 in ws, m5..m8 in out; column-halved chain ----
        float* fbig = (float*)big;
        float* mpow[ORDER + 1];
        for (int k = 1; k <= 4; ++k) mpow[k] = fbig + (size_t)(k - 1) * NB;
        for (int k = 5; k <= 8; ++k) mpow[k] = out + (size_t)(k - 5) * NB;

        hipMemsetAsync(col_of_node, 0xFF, (size_t)N_NODES * 4, stream);
        hipMemsetAsync(flag, 0, (size_t)N_NODES * 4, stream);
        hipMemsetAsync(mpow[1], 0, NB * 4, stream);
        colmap_kernel<<<1, 256, 0, stream>>>(bi, col_of_node, next_dup);
        m1_edges_kernel<<<eb, 256, 0, stream>>>(src, dst, ew, col_of_node, next_dup,
                                                mpow[1], flag, E);
        for (int h = 0; h < 2; ++h) {
            int colOff = h * 128;
            for (int k = 2; k <= ORDER; ++k) {
                spmm_half<<<nodeGrid, 256, 0, stream>>>(mpow[k - 1], mpow[k],
                                                        rowStart, counts, csr_pair, colOff);
            }
        }
        combine_kernel<<<cgrid, 256, 0, stream>>>(out, fbig, coeffs, bi);
    }
}

// Round 6
// 2021.883 us; speedup vs baseline: 2.3261x; 1.0267x over previous
//
#include <hip/hip_runtime.h>

#define N_NODES 100000
#define BATCH   256
#define NUM_TAU 4
#define ORDER   8
#define NB      ((size_t)N_NODES * BATCH)   // 25,600,000 elements per tau slice
#define NBUK    98                          // buckets of 1024 nodes (dst>>10)
#define NBLK    391                         // ceil(N_NODES/256) for scans

__device__ __forceinline__ unsigned short f2bf(float f) {
    unsigned int u = __float_as_uint(f);
    u += 0x7FFFu + ((u >> 16) & 1u);   // round-to-nearest-even
    return (unsigned short)(u >> 16);
}
__device__ __forceinline__ float bf2f(unsigned short h) {
    return __uint_as_float((unsigned int)h << 16);
}

// ---------------- CSR build: ordered rowStart + bucketed 2-pass scatter ----------------

__global__ void hist_kernel(const int* __restrict__ dst, int* __restrict__ counts, int E) {
    int e = blockIdx.x * blockDim.x + threadIdx.x;
    if (e < E) atomicAdd(&counts[dst[e]], 1);
}

// prefix-sum of counts -> rowStart (ordered by node index)
__global__ void scan1(const int* __restrict__ counts, int* __restrict__ blockSum) {
    __shared__ int s[256];
    int n = blockIdx.x * 256 + threadIdx.x;
    s[threadIdx.x] = (n < N_NODES) ? counts[n] : 0;
    __syncthreads();
    for (int st = 128; st > 0; st >>= 1) {
        if (threadIdx.x < st) s[threadIdx.x] += s[threadIdx.x + st];
        __syncthreads();
    }
    if (threadIdx.x == 0) blockSum[blockIdx.x] = s[0];
}

__global__ void scan2(int* __restrict__ blockSum) {   // in-place exclusive scan of NBLK values
    __shared__ int s[512];
    int t = threadIdx.x;
    int v = (t < NBLK) ? blockSum[t] : 0;
    s[t] = v;
    __syncthreads();
    for (int st = 1; st < 512; st <<= 1) {
        int u = (t >= st) ? s[t - st] : 0;
        __syncthreads();
        s[t] += u;
        __syncthreads();
    }
    if (t < NBLK) blockSum[t] = s[t] - v;
}

__global__ void scan3(const int* __restrict__ counts, const int* __restrict__ blockSumEx,
                      int* __restrict__ rowStart) {
    __shared__ int s[256];
    int n = blockIdx.x * 256 + threadIdx.x;
    int v = (n < N_NODES) ? counts[n] : 0;
    s[threadIdx.x] = v;
    __syncthreads();
    for (int st = 1; st < 256; st <<= 1) {
        int u = (threadIdx.x >= st) ? s[threadIdx.x - st] : 0;
        __syncthreads();
        s[threadIdx.x] += u;
        __syncthreads();
    }
    if (n < N_NODES) rowStart[n] = blockSumEx[blockIdx.x] + s[threadIdx.x] - v;
}

__global__ void initcur_kernel(const int* __restrict__ rowStart, int* __restrict__ cursor,
                               int* __restrict__ bcur) {
    int n = blockIdx.x * 256 + threadIdx.x;
    if (n < N_NODES) cursor[n] = rowStart[n];
    if (n < NBUK) bcur[n] = rowStart[n << 10];
}

#define EPT 16
__global__ void bucketize_kernel(const int* __restrict__ src, const int* __restrict__ dst,
                                 const float* __restrict__ w, int* __restrict__ bcur,
                                 int2* __restrict__ isw, int* __restrict__ idn, int E) {
    __shared__ int cnt[NBUK], base[NBUK], off[NBUK];
    int e0 = blockIdx.x * (256 * EPT);
    for (int i = threadIdx.x; i < NBUK; i += 256) { cnt[i] = 0; off[i] = 0; }
    __syncthreads();
    #pragma unroll
    for (int i = 0; i < EPT; ++i) {
        int e = e0 + i * 256 + threadIdx.x;
        if (e < E) atomicAdd(&cnt[dst[e] >> 10], 1);
    }
    __syncthreads();
    for (int i = threadIdx.x; i < NBUK; i += 256) {
        int c = cnt[i];
        base[i] = c ? atomicAdd(&bcur[i], c) : 0;
    }
    __syncthreads();
    #pragma unroll
    for (int i = 0; i < EPT; ++i) {
        int e = e0 + i * 256 + threadIdx.x;
        if (e < E) {
            int d = dst[e];
            int b = d >> 10;
            int p = base[b] + atomicAdd(&off[b], 1);
            isw[p] = make_int2(src[e], __float_as_int(w[e]));
            idn[p] = d;
        }
    }
}

__global__ void place_kernel(const int2* __restrict__ isw, const int* __restrict__ idn,
                             int* __restrict__ cursor, int2* __restrict__ csr_pair, int E) {
    int e = blockIdx.x * blockDim.x + threadIdx.x;
    if (e < E) {
        int d = idn[e];
        int p = atomicAdd(&cursor[d], 1);
        csr_pair[p] = isw[e];
    }
}

// ---------------- sparse m1 = A @ onehot  (m1 fp32, lives in out slice 0) ----------------

__global__ void colmap_kernel(const int* __restrict__ bi, int* __restrict__ col_of_node,
                              int* __restrict__ next_dup) {
    int j = threadIdx.x;  // 256
    int prev = atomicExch(&col_of_node[bi[j]], j);
    next_dup[j] = prev;
}

__global__ void m1_edges_kernel(const int* __restrict__ src, const int* __restrict__ dst,
                                const float* __restrict__ w,
                                const int* __restrict__ col_of_node,
                                const int* __restrict__ next_dup,
                                float* __restrict__ m1, int* __restrict__ flag, int E) {
    int e = blockIdx.x * blockDim.x + threadIdx.x;
    if (e >= E) return;
    int j = col_of_node[src[e]];
    if (j < 0) return;
    float we = w[e];
    int d = dst[e];
    flag[d] = 1;
    size_t rb = (size_t)d * BATCH;
    while (j >= 0) {
        atomicAdd(&m1[rb + j], we);
        j = next_dup[j];
    }
}

// ---------------- k=2: fp32 m1 (sparse rows, flag-skipped) -> bf16 m2 ----------------
__global__ void spmm_k2(const float* __restrict__ m1, unsigned short* __restrict__ m2,
                        const int* __restrict__ rowStart, const int* __restrict__ counts,
                        const int2* __restrict__ csr_pair, const int* __restrict__ flag) {
    int wave = threadIdx.x >> 6;
    int lane = threadIdx.x & 63;
    int node = blockIdx.x * 4 + wave;
    if (node >= N_NODES) return;
    int col0 = lane * 4;

    int start = rowStart[node];
    int len   = counts[node];

    float4 acc = make_float4(0.f, 0.f, 0.f, 0.f);
    for (int i = 0; i < len; ++i) {
        int2 pr = csr_pair[start + i];
        if (flag[pr.x]) {
            float w = __int_as_float(pr.y);
            float4 v = *(const float4*)(m1 + (size_t)pr.x * BATCH + col0);
            acc.x += w * v.x; acc.y += w * v.y; acc.z += w * v.z; acc.w += w * v.w;
        }
    }
    ushort4 o;
    o.x = f2bf(acc.x); o.y = f2bf(acc.y); o.z = f2bf(acc.z); o.w = f2bf(acc.w);
    *(ushort4*)(m2 + (size_t)node * BATCH + col0) = o;
}

// ---------------- bf16 -> bf16 SpMM, 8-deep gather pipeline ----------------
__global__ void spmm_bf(const unsigned short* __restrict__ min_, unsigned short* __restrict__ mout,
                        const int* __restrict__ rowStart, const int* __restrict__ counts,
                        const int2* __restrict__ csr_pair) {
    int wave = threadIdx.x >> 6;
    int lane = threadIdx.x & 63;
    int node = blockIdx.x * 4 + wave;
    if (node >= N_NODES) return;
    int col0 = lane * 4;

    int start = rowStart[node];
    int len   = counts[node];

    float4 acc = make_float4(0.f, 0.f, 0.f, 0.f);
    int i = 0;
    for (; i + 8 <= len; i += 8) {
        int2 pr[8];
        #pragma unroll
        for (int u = 0; u < 8; ++u) pr[u] = csr_pair[start + i + u];
        ushort4 v[8];
        #pragma unroll
        for (int u = 0; u < 8; ++u)
            v[u] = *(const ushort4*)(min_ + (size_t)pr[u].x * BATCH + col0);
        #pragma unroll
        for (int u = 0; u < 8; ++u) {
            float w = __int_as_float(pr[u].y);
            acc.x += w * bf2f(v[u].x);
            acc.y += w * bf2f(v[u].y);
            acc.z += w * bf2f(v[u].z);
            acc.w += w * bf2f(v[u].w);
        }
    }
    for (; i < len; ++i) {
        int2 pr = csr_pair[start + i];
        float w = __int_as_float(pr.y);
        ushort4 v = *(const ushort4*)(min_ + (size_t)pr.x * BATCH + col0);
        acc.x += w * bf2f(v.x);
        acc.y += w * bf2f(v.y);
        acc.z += w * bf2f(v.z);
        acc.w += w * bf2f(v.w);
    }
    ushort4 o;
    o.x = f2bf(acc.x); o.y = f2bf(acc.y); o.z = f2bf(acc.z); o.w = f2bf(acc.w);
    *(ushort4*)(mout + (size_t)node * BATCH + col0) = o;
}

// ---------------- combine: out[t] = c[t,0]*onehot + c[t,1]*m1 + sum_{k>=2} c[t,k]*m_k ----------------
__global__ void combine_bf(float* __restrict__ out, const unsigned short* __restrict__ m28,
                           const float* __restrict__ coeffs, const int* __restrict__ bi) {
    size_t tid = (size_t)blockIdx.x * blockDim.x + threadIdx.x;
    size_t base = tid * 4;
    if (base >= NB) return;
    int node = (int)(base >> 8);
    int j0   = (int)(base & 255);

    float4 p[ORDER];
    p[0] = *(const float4*)(out + base);  // m1 (slice 0, in-place)
    #pragma unroll
    for (int k = 2; k <= ORDER; ++k) {
        ushort4 v = *(const ushort4*)(m28 + (size_t)(k - 2) * NB + base);
        p[k - 1] = make_float4(bf2f(v.x), bf2f(v.y), bf2f(v.z), bf2f(v.w));
    }

    float oh[4];
    #pragma unroll
    for (int i = 0; i < 4; ++i) oh[i] = (bi[j0 + i] == node) ? 1.0f : 0.0f;

    #pragma unroll
    for (int t = 0; t < NUM_TAU; ++t) {
        float c0 = coeffs[t * (ORDER + 1)];
        float4 o = make_float4(c0 * oh[0], c0 * oh[1], c0 * oh[2], c0 * oh[3]);
        #pragma unroll
        for (int k = 1; k <= ORDER; ++k) {
            float c = coeffs[t * (ORDER + 1) + k];
            o.x += c * p[k - 1].x;
            o.y += c * p[k - 1].y;
            o.z += c * p[k - 1].z;
            o.w += c * p[k - 1].w;
        }
        *(float4*)(out + (size_t)t * NB + base) = o;
    }
}

// ---------------- fallback scheme B (fp32 path) ----------------

__global__ void spmm_half(const float* __restrict__ min_, float* __restrict__ mout,
                          const int* __restrict__ rowStart, const int* __restrict__ counts,
                          const int2* __restrict__ csr_pair, int colOff) {
    int wave = threadIdx.x >> 6;
    int lane = threadIdx.x & 63;
    int node = blockIdx.x * 4 + wave;
    if (node >= N_NODES) return;
    int c = colOff + lane * 2;
    int start = rowStart[node];
    int len   = counts[node];
    float2 acc = make_float2(0.f, 0.f);
    int i = 0;
    for (; i + 8 <= len; i += 8) {
        int2 pr[8];
        #pragma unroll
        for (int u = 0; u < 8; ++u) pr[u] = csr_pair[start + i + u];
        float2 v[8];
        #pragma unroll
        for (int u = 0; u < 8; ++u)
            v[u] = *(const float2*)(min_ + (size_t)pr[u].x * BATCH + c);
        #pragma unroll
        for (int u = 0; u < 8; ++u) {
            float w = __int_as_float(pr[u].y);
            acc.x += w * v[u].x;
            acc.y += w * v[u].y;
        }
    }
    for (; i < len; ++i) {
        int2 pr = csr_pair[start + i];
        float w = __int_as_float(pr.y);
        float2 v = *(const float2*)(min_ + (size_t)pr.x * BATCH + c);
        acc.x += w * v.x;
        acc.y += w * v.y;
    }
    *(float2*)(mout + (size_t)node * BATCH + c) = acc;
}

__global__ void combine_kernel(float* __restrict__ out, const float* __restrict__ m14,
                               const float* __restrict__ coeffs, const int* __restrict__ bi) {
    size_t tid = (size_t)blockIdx.x * blockDim.x + threadIdx.x;
    size_t base = tid * 4;
    if (base >= NB) return;
    int node = (int)(base >> 8);
    int j0   = (int)(base & 255);
    float4 p[ORDER];
    #pragma unroll
    for (int k = 1; k <= 4; ++k)
        p[k - 1] = *(const float4*)(m14 + (size_t)(k - 1) * NB + base);
    #pragma unroll
    for (int k = 5; k <= 8; ++k)
        p[k - 1] = *(const float4*)(out + (size_t)(k - 5) * NB + base);
    float oh[4];
    #pragma unroll
    for (int i = 0; i < 4; ++i) oh[i] = (bi[j0 + i] == node) ? 1.0f : 0.0f;
    #pragma unroll
    for (int t = 0; t < NUM_TAU; ++t) {
        float c0 = coeffs[t * (ORDER + 1)];
        float4 o = make_float4(c0 * oh[0], c0 * oh[1], c0 * oh[2], c0 * oh[3]);
        #pragma unroll
        for (int k = 1; k <= ORDER; ++k) {
            float c = coeffs[t * (ORDER + 1) + k];
            o.x += c * p[k - 1].x;
            o.y += c * p[k - 1].y;
            o.z += c * p[k - 1].z;
            o.w += c * p[k - 1].w;
        }
        *(float4*)(out + (size_t)t * NB + base) = o;
    }
}

extern "C" void kernel_launch(void* const* d_in, const int* in_sizes, int n_in,
                              void* d_out, int out_size, void* d_ws, size_t ws_size,
                              hipStream_t stream) {
    const float* coeffs = (const float*)d_in[0];
    const float* ew     = (const float*)d_in[1];
    const int*   src    = (const int*)d_in[2];
    const int*   dst    = (const int*)d_in[3];
    const int*   bi     = (const int*)d_in[4];   // int32 on device (JAX x64 disabled)
    const int E = in_sizes[1];

    float* out = (float*)d_out;

    auto align_up = [](uintptr_t v, uintptr_t a) { return (v + a - 1) & ~(a - 1); };

    uintptr_t p0 = (uintptr_t)d_ws;
    int* counts      = (int*)p0;  p0 += (size_t)N_NODES * 4;  p0 = align_up(p0, 256);
    int* rowStart    = (int*)p0;  p0 += (size_t)N_NODES * 4;  p0 = align_up(p0, 256);
    int* cursor      = (int*)p0;  p0 += (size_t)N_NODES * 4;  p0 = align_up(p0, 256);
    int* blockSum    = (int*)p0;  p0 += (size_t)NBLK * 4;     p0 = align_up(p0, 256);
    int* bcur        = (int*)p0;  p0 += (size_t)NBUK * 4;     p0 = align_up(p0, 256);
    int* col_of_node = (int*)p0;  p0 += (size_t)N_NODES * 4;  p0 = align_up(p0, 256);
    int* next_dup    = (int*)p0;  p0 += 1024;                 p0 = align_up(p0, 256);
    int* flag        = (int*)p0;  p0 += (size_t)N_NODES * 4;  p0 = align_up(p0, 256);
    int2* csr_pair   = (int2*)p0; p0 += (size_t)E * 8;        p0 = align_up(p0, 256);
    void* big        = (void*)p0;
    size_t big_bytes = ((uintptr_t)d_ws + ws_size > p0) ? ((uintptr_t)d_ws + ws_size - p0) : 0;

    int eb = (E + 255) / 256;
    int nodeGrid = (N_NODES + 3) / 4;
    int cgrid = (int)((NB / 4 + 255) / 256);

    // ---- CSR build (shared by both schemes) ----
    // intermediate bucket-grouped edge buffer overlaps the tail of `big`
    // (that region is only written by the k>=6 spmm steps, long after place_kernel).
    bool schemeA = (big_bytes >= 7 * NB * 2);
    uintptr_t ibase;
    if (schemeA) ibase = (uintptr_t)big + 5 * NB * 2;              // m7/m8 region: 102 MB
    else         ibase = (uintptr_t)big + 3 * NB * 4;              // m4 region: 102 MB
    ibase = align_up(ibase, 256);
    int2* isw = (int2*)ibase;
    int*  idn = (int*)(ibase + (size_t)E * 8);

    hipMemsetAsync(counts, 0, (size_t)N_NODES * 4, stream);
    hist_kernel<<<eb, 256, 0, stream>>>(dst, counts, E);
    scan1<<<NBLK, 256, 0, stream>>>(counts, blockSum);
    scan2<<<1, 512, 0, stream>>>(blockSum);
    scan3<<<NBLK, 256, 0, stream>>>(counts, blockSum, rowStart);
    initcur_kernel<<<NBLK, 256, 0, stream>>>(rowStart, cursor, bcur);
    bucketize_kernel<<<(E + 256 * EPT - 1) / (256 * EPT), 256, 0, stream>>>(
        src, dst, ew, bcur, isw, idn, E);
    place_kernel<<<eb, 256, 0, stream>>>(isw, idn, cursor, csr_pair, E);

    if (schemeA) {
        // ---- scheme A (bf16 chain): m1 fp32 in out slice 0, m2..m8 bf16 in ws ----
        unsigned short* m28 = (unsigned short*)big;
        float* m1 = out;  // slice 0

        hipMemsetAsync(col_of_node, 0xFF, (size_t)N_NODES * 4, stream);
        hipMemsetAsync(flag, 0, (size_t)N_NODES * 4, stream);
        hipMemsetAsync(m1, 0, NB * 4, stream);

        colmap_kernel<<<1, 256, 0, stream>>>(bi, col_of_node, next_dup);
        m1_edges_kernel<<<eb, 256, 0, stream>>>(src, dst, ew, col_of_node, next_dup,
                                                m1, flag, E);
        spmm_k2<<<nodeGrid, 256, 0, stream>>>(m1, m28, rowStart, counts, csr_pair, flag);
        for (int k = 3; k <= ORDER; ++k) {
            spmm_bf<<<nodeGrid, 256, 0, stream>>>(m28 + (size_t)(k - 3) * NB,
                                                  m28 + (size_t)(k - 2) * NB,
                                                  rowStart, counts, csr_pair);
        }
        combine_bf<<<cgrid, 256, 0, stream>>>(out, m28, coeffs, bi);
    } else {
        // ---- scheme B (fp32): m1..m4 in ws, m5..m8 in out; column-halved chain ----
        float* fbig = (float*)big;
        float* mpow[ORDER + 1];
        for (int k = 1; k <= 4; ++k) mpow[k] = fbig + (size_t)(k - 1) * NB;
        for (int k = 5; k <= 8; ++k) mpow[k] = out + (size_t)(k - 5) * NB;

        hipMemsetAsync(col_of_node, 0xFF, (size_t)N_NODES * 4, stream);
        hipMemsetAsync(flag, 0, (size_t)N_NODES * 4, stream);
        hipMemsetAsync(mpow[1], 0, NB * 4, stream);
        colmap_kernel<<<1, 256, 0, stream>>>(bi, col_of_node, next_dup);
        m1_edges_kernel<<<eb, 256, 0, stream>>>(src, dst, ew, col_of_node, next_dup,
                                                mpow[1], flag, E);
        for (int h = 0; h < 2; ++h) {
            int colOff = h * 128;
            for (int k = 2; k <= ORDER; ++k) {
                spmm_half<<<nodeGrid, 256, 0, stream>>>(mpow[k - 1], mpow[k],
                                                        rowStart, counts, csr_pair, colOff);
            }
        }
        combine_kernel<<<cgrid, 256, 0, stream>>>(out, fbig, coeffs, bi);
    }
}